// Round 1
// baseline (1211.085 us; speedup 1.0000x reference)
//
#include <hip/hip_runtime.h>

typedef __bf16 bf16x8 __attribute__((ext_vector_type(8)));
typedef float f32x4 __attribute__((ext_vector_type(4)));
typedef unsigned short u16;
typedef unsigned short u16x8 __attribute__((ext_vector_type(8)));

#define DIM 4096
#define NHEADS 32
#define NKV 8
#define HD 128
#define BB 2
#define SS 2048
#define MROWS (BB*SS)        // 4096
#define KVPITCH (2*NKV*HD)   // 2048
#define QSCALE 0.08838834764831843f  // 1/sqrt(128)

__device__ __forceinline__ u16 f2bf(float f) {
  unsigned int u = __float_as_uint(f);
  u += 0x7fffu + ((u >> 16) & 1u);   // round-to-nearest-even
  return (u16)(u >> 16);
}

__device__ __forceinline__ void gload16(const void* g, void* l) {
  __builtin_amdgcn_global_load_lds(
      (const __attribute__((address_space(1))) unsigned int*)g,
      (__attribute__((address_space(3))) unsigned int*)l, 16, 0, 0);
}

// ---------------- fp32 -> bf16 conversion (8 elems/thread) ----------------
__global__ __launch_bounds__(256) void f2b_kernel(const float* __restrict__ in,
                                                  u16* __restrict__ out, int n8) {
  int i = blockIdx.x * 256 + threadIdx.x;
  if (i >= n8) return;
  const float4* in4 = (const float4*)in;
  float4 a = in4[2*(size_t)i];
  float4 b = in4[2*(size_t)i + 1];
  u16x8 o;
  o[0]=f2bf(a.x); o[1]=f2bf(a.y); o[2]=f2bf(a.z); o[3]=f2bf(a.w);
  o[4]=f2bf(b.x); o[5]=f2bf(b.y); o[6]=f2bf(b.z); o[7]=f2bf(b.w);
  ((u16x8*)out)[i] = o;
}

// ---------------- C[M][N] = A[M][K] @ B[N][K]^T  (m97 structure) ----------------
// 128x128 tile, BK=32, 256 threads = 4 waves (2x2), global_load_lds width 16.
template<int OUTF32>
__global__ __launch_bounds__(256) void gemm_bt(
    const u16* __restrict__ A, const u16* __restrict__ Bm, void* __restrict__ C,
    int M, int N, int K, float alpha) {
  __shared__ u16 As[128*32];
  __shared__ u16 Bs[128*32];
  const int t = threadIdx.x;
  const int l = t & 63, w = t >> 6;
  const int l15 = l & 15, l4 = l >> 4;
  const int row0 = blockIdx.y * 128, col0 = blockIdx.x * 128;
  const int wr = (w >> 1) * 64, wc = (w & 1) * 64;
  f32x4 acc[4][4] = {};
  const int o0 = w*1024 + l*16;

  for (int k0 = 0; k0 < K; k0 += 32) {
    #pragma unroll
    for (int i = 0; i < 2; ++i) {
      int o = i*4096 + o0;
      int r = o >> 6;          // tile row (64B per row of 32 bf16)
      int cb = o & 63;         // byte within row
      gload16((const char*)A + ((size_t)(row0 + r)*K + k0)*2 + cb,
              (char*)As + i*4096 + w*1024);
      gload16((const char*)Bm + ((size_t)(col0 + r)*K + k0)*2 + cb,
              (char*)Bs + i*4096 + w*1024);
    }
    __syncthreads();
    bf16x8 af[4], bfr[4];
    #pragma unroll
    for (int mi = 0; mi < 4; ++mi)
      af[mi] = *(const bf16x8*)&As[(wr + mi*16 + l15)*32 + l4*8];
    #pragma unroll
    for (int ni = 0; ni < 4; ++ni)
      bfr[ni] = *(const bf16x8*)&Bs[(wc + ni*16 + l15)*32 + l4*8];
    #pragma unroll
    for (int mi = 0; mi < 4; ++mi)
      #pragma unroll
      for (int ni = 0; ni < 4; ++ni)
        acc[mi][ni] = __builtin_amdgcn_mfma_f32_16x16x32_bf16(af[mi], bfr[ni], acc[mi][ni], 0, 0, 0);
    __syncthreads();
  }

  // epilogue: C/D layout col=lane&15, row=(lane>>4)*4+reg
  #pragma unroll
  for (int mi = 0; mi < 4; ++mi) {
    #pragma unroll
    for (int ni = 0; ni < 4; ++ni) {
      #pragma unroll
      for (int r = 0; r < 4; ++r) {
        size_t rr = (size_t)(row0 + wr + mi*16 + l4*4 + r);
        size_t cc = (size_t)(col0 + wc + ni*16 + l15);
        float v = acc[mi][ni][r] * alpha;
        if (OUTF32) ((float*)C)[rr*(size_t)N + cc] = v;
        else        ((u16*)C)[rr*(size_t)N + cc] = f2bf(v);
      }
    }
  }
}

// ---------------- causal GQA flash attention ----------------
// grid (qb=16, h=32, b=2), 256 threads = 4 waves; wave w owns q rows [w*32, w*32+32).
// Q pre-scaled by 1/sqrt(128). KVB=32 per step.
__global__ __launch_bounds__(256) void attn_kernel(
    const u16* __restrict__ Q,   // [4096][4096]  (b,s, h*128+d)
    const u16* __restrict__ KV,  // [4096][2048]  (b,s, k: hkv*128+d | v: 1024+hkv*128+d)
    u16* __restrict__ O) {       // [4096][4096]
  __shared__ u16 Ks[32*128];     // swizzled content: byte ^= (row&7)<<4
  __shared__ u16 Vt[128*40];     // V^T, row stride 40, kv-group XOR swizzle
  __shared__ u16 Ps[4][32*40];   // per-wave P tile
  const int t = threadIdx.x;
  const int l = t & 63, w = t >> 6;
  const int l15 = l & 15, l4 = l >> 4;
  const int qb = blockIdx.x, h = blockIdx.y, b = blockIdx.z;
  const int q0 = qb * 128;
  const int hkv = h >> 2;

  // Q fragments in registers: A-operand row=lane&15, k=(lane>>4)*8+j
  const size_t qbase = ((size_t)(b*SS + q0 + w*32)) * DIM + h*HD;
  bf16x8 qf[2][4];
  #pragma unroll
  for (int m = 0; m < 2; ++m)
    #pragma unroll
    for (int kd = 0; kd < 4; ++kd)
      qf[m][kd] = *(const bf16x8*)&Q[qbase + (size_t)(m*16 + l15)*DIM + kd*32 + l4*8];

  f32x4 oacc[2][8] = {};
  float mrun[2][4], lrun[2][4];
  #pragma unroll
  for (int m = 0; m < 2; ++m)
    #pragma unroll
    for (int r = 0; r < 4; ++r) { mrun[m][r] = -1e30f; lrun[m][r] = 0.f; }

  const u16* Kg = KV + (size_t)(b*SS) * KVPITCH + hkv*HD;
  const u16* Vg = Kg + NKV*HD;
  const int nsteps = (qb << 2) + 4;

  for (int st = 0; st < nsteps; ++st) {
    const int kv0 = st << 5;
    // --- stage K tile [32][128]: linear LDS dest, pre-swizzled global source
    #pragma unroll
    for (int i = 0; i < 2; ++i) {
      int o = i*4096 + w*1024 + l*16;
      int row = o >> 8;              // 256B per row
      int chunk = (o >> 4) & 15;
      int sc = chunk ^ (row & 7);
      gload16((const char*)(Kg + (size_t)(kv0 + row) * KVPITCH) + sc*16,
              (char*)Ks + i*4096 + w*1024);
    }
    // --- stage V^T [128][40] (reg-staged; swizzle kv by (d>>3)&3 on bits 3-4)
    #pragma unroll
    for (int c = 0; c < 2; ++c) {
      int kv = c*16 + (t >> 4);
      int d0 = (t & 15) * 8;
      u16x8 vv = *(const u16x8*)(Vg + (size_t)(kv0 + kv) * KVPITCH + d0);
      int kvx = kv ^ (((t & 15) & 3) << 3);   // s = (d>>3)&3 = (t&15)&3
      #pragma unroll
      for (int j = 0; j < 8; ++j)
        Vt[(d0 + j)*40 + kvx] = vv[j];
    }
    __syncthreads();

    // --- QK^T
    f32x4 sacc[2][2] = {};
    #pragma unroll
    for (int kd = 0; kd < 4; ++kd) {
      bf16x8 kf[2];
      #pragma unroll
      for (int n = 0; n < 2; ++n) {
        int row = n*16 + l15;
        int off = (row << 8) | (((kd*4 + l4) ^ (row & 7)) << 4);
        kf[n] = *(const bf16x8*)((const char*)Ks + off);
      }
      #pragma unroll
      for (int m = 0; m < 2; ++m)
        #pragma unroll
        for (int n = 0; n < 2; ++n)
          sacc[m][n] = __builtin_amdgcn_mfma_f32_16x16x32_bf16(qf[m][kd], kf[n], sacc[m][n], 0, 0, 0);
    }

    // --- causal mask (only the last 4 tiles can cross the diagonal)
    if (st >= (qb << 2)) {
      #pragma unroll
      for (int n = 0; n < 2; ++n) {
        int ki = kv0 + n*16 + l15;
        #pragma unroll
        for (int m = 0; m < 2; ++m) {
          #pragma unroll
          for (int r = 0; r < 4; ++r) {
            int qi = q0 + w*32 + m*16 + l4*4 + r;
            if (ki > qi) sacc[m][n][r] = -1e30f;
          }
        }
      }
    }

    // --- online softmax (row lives across the 16 lanes of each lane-group)
    #pragma unroll
    for (int m = 0; m < 2; ++m) {
      #pragma unroll
      for (int r = 0; r < 4; ++r) {
        float s0 = sacc[m][0][r], s1 = sacc[m][1][r];
        float vm = fmaxf(s0, s1);
        #pragma unroll
        for (int off = 1; off < 16; off <<= 1) vm = fmaxf(vm, __shfl_xor(vm, off));
        float mnew = fmaxf(mrun[m][r], vm);
        float al = __expf(mrun[m][r] - mnew);
        float p0 = __expf(s0 - mnew);
        float p1 = __expf(s1 - mnew);
        float rs = p0 + p1;
        #pragma unroll
        for (int off = 1; off < 16; off <<= 1) rs += __shfl_xor(rs, off);
        mrun[m][r] = mnew;
        lrun[m][r] = lrun[m][r] * al + rs;
        #pragma unroll
        for (int dn = 0; dn < 8; ++dn) oacc[m][dn][r] *= al;
        int prow = m*16 + l4*4 + r;
        Ps[w][prow*40 + l15]      = f2bf(p0);
        Ps[w][prow*40 + 16 + l15] = f2bf(p1);
      }
    }

    // --- PV
    #pragma unroll
    for (int m = 0; m < 2; ++m) {
      bf16x8 pf = *(const bf16x8*)&Ps[w][(m*16 + l15)*40 + l4*8];
      #pragma unroll
      for (int dn = 0; dn < 8; ++dn) {
        int d = dn*16 + l15;
        int kvg = ((l4 ^ ((d >> 3) & 3)) << 3);
        bf16x8 vf = *(const bf16x8*)&Vt[d*40 + kvg];
        oacc[m][dn] = __builtin_amdgcn_mfma_f32_16x16x32_bf16(pf, vf, oacc[m][dn], 0, 0, 0);
      }
    }
    __syncthreads();
  }

  // --- epilogue
  const size_t obase = ((size_t)(b*SS + q0 + w*32)) * DIM + h*HD;
  #pragma unroll
  for (int m = 0; m < 2; ++m) {
    #pragma unroll
    for (int r = 0; r < 4; ++r) {
      float inv = 1.0f / lrun[m][r];
      int srow = m*16 + l4*4 + r;
      #pragma unroll
      for (int dn = 0; dn < 8; ++dn)
        O[obase + (size_t)srow*DIM + dn*16 + l15] = f2bf(oacc[m][dn][r] * inv);
    }
  }
}

extern "C" void kernel_launch(void* const* d_in, const int* in_sizes, int n_in,
                              void* d_out, int out_size, void* d_ws, size_t ws_size,
                              hipStream_t stream) {
  const float* x   = (const float*)d_in[0];
  const float* Wq  = (const float*)d_in[1];
  const float* Wkv = (const float*)d_in[2];
  const float* Wo  = (const float*)d_in[3];
  // start_pos (d_in[4]) is 0 for prefill; causal indexing assumes it.

  if (ws_size < (160ull << 20)) return;  // need 160 MB scratch
  char* ws = (char*)d_ws;
  u16* xb   = (u16*)(ws);                  // 32 MB  [4096][4096]
  u16* Wqb  = (u16*)(ws + (32ull  << 20)); // 32 MB  [4096][4096]
  u16* Wkvb = (u16*)(ws + (64ull  << 20)); // 16 MB  [2048][4096]
  u16* Wob  = (u16*)(ws + (80ull  << 20)); // 32 MB  [4096][4096]
  u16* Qb   = (u16*)(ws + (112ull << 20)); // 32 MB  [4096][4096]
  u16* KVb  = (u16*)(ws + (144ull << 20)); // 16 MB  [4096][2048]
  u16* attnb = xb;                         // alias: x no longer needed post-GEMMs

  // fp32 -> bf16
  f2b_kernel<<<8192, 256, 0, stream>>>(x,   xb,   2097152);
  f2b_kernel<<<8192, 256, 0, stream>>>(Wq,  Wqb,  2097152);
  f2b_kernel<<<4096, 256, 0, stream>>>(Wkv, Wkvb, 1048576);
  f2b_kernel<<<8192, 256, 0, stream>>>(Wo,  Wob,  2097152);

  // projections (scale fused into Q)
  gemm_bt<0><<<dim3(32, 32), 256, 0, stream>>>(xb, Wqb,  Qb,  MROWS, 4096, DIM, QSCALE);
  gemm_bt<0><<<dim3(16, 32), 256, 0, stream>>>(xb, Wkvb, KVb, MROWS, 2048, DIM, 1.0f);

  // causal GQA flash attention
  attn_kernel<<<dim3(16, NHEADS, BB), 256, 0, stream>>>(Qb, KVb, attnb);

  // output projection (fp32 out)
  gemm_bt<1><<<dim3(32, 32), 256, 0, stream>>>(attnb, Wob, d_out, MROWS, 4096, DIM, 1.0f);
}

// Round 2
// 709.537 us; speedup vs baseline: 1.7069x; 1.7069x over previous
//
#include <hip/hip_runtime.h>

typedef __bf16 bf16x8 __attribute__((ext_vector_type(8)));
typedef __bf16 bf16x4 __attribute__((ext_vector_type(4)));
typedef float f32x4 __attribute__((ext_vector_type(4)));
typedef unsigned short u16;
typedef unsigned short u16x8 __attribute__((ext_vector_type(8)));

#define DIM 4096
#define NHEADS 32
#define NKV 8
#define HD 128
#define BB 2
#define SS 2048
#define MROWS (BB*SS)        // 4096
#define KVPITCH (2*NKV*HD)   // 2048
#define QSCALE 0.08838834764831843f  // 1/sqrt(128)

#define WAIT_LGKM0 asm volatile("s_waitcnt lgkmcnt(0)" ::: "memory")
#define WAIT_VM0   asm volatile("s_waitcnt vmcnt(0)" ::: "memory")
#define SGB0       __builtin_amdgcn_sched_barrier(0)

__device__ __forceinline__ u16 f2bf(float f) {
  unsigned int u = __float_as_uint(f);
  u += 0x7fffu + ((u >> 16) & 1u);   // round-to-nearest-even
  return (u16)(u >> 16);
}

__device__ __forceinline__ void gload16(const void* g, void* l) {
  __builtin_amdgcn_global_load_lds(
      (const __attribute__((address_space(1))) unsigned int*)g,
      (__attribute__((address_space(3))) unsigned int*)l, 16, 0, 0);
}

// hardware transpose read: lane group of 16 supplies 16 consecutive 8B chunks
// covering a [4 rows][16 cols] bf16 subtile; lane receives column (lane&15).
__device__ __forceinline__ bf16x4 tr16(const void* p) {
  bf16x4 d;
  asm volatile("ds_read_b64_tr_b16 %0, %1"
               : "=v"(d)
               : "v"((const __attribute__((address_space(3))) u16*)p)
               : "memory");
  return d;
}

// rotate within each 16-lane row (VALU pipe, not DS)
template<int CTRL>
__device__ __forceinline__ float dpp_ror(float x) {
  return __int_as_float(__builtin_amdgcn_update_dpp(
      0, __float_as_int(x), CTRL, 0xF, 0xF, false));
}
__device__ __forceinline__ float red16_max(float v) {
  v = fmaxf(v, dpp_ror<0x121>(v));
  v = fmaxf(v, dpp_ror<0x122>(v));
  v = fmaxf(v, dpp_ror<0x124>(v));
  v = fmaxf(v, dpp_ror<0x128>(v));
  return v;
}
__device__ __forceinline__ float red16_sum(float v) {
  v += dpp_ror<0x121>(v);
  v += dpp_ror<0x122>(v);
  v += dpp_ror<0x124>(v);
  v += dpp_ror<0x128>(v);
  return v;
}

// ---------------- fp32 -> bf16 conversion (8 elems/thread) ----------------
__global__ __launch_bounds__(256) void f2b_kernel(const float* __restrict__ in,
                                                  u16* __restrict__ out, int n8) {
  int i = blockIdx.x * 256 + threadIdx.x;
  if (i >= n8) return;
  const float4* in4 = (const float4*)in;
  float4 a = in4[2*(size_t)i];
  float4 b = in4[2*(size_t)i + 1];
  u16x8 o;
  o[0]=f2bf(a.x); o[1]=f2bf(a.y); o[2]=f2bf(a.z); o[3]=f2bf(a.w);
  o[4]=f2bf(b.x); o[5]=f2bf(b.y); o[6]=f2bf(b.z); o[7]=f2bf(b.w);
  ((u16x8*)out)[i] = o;
}

// ---------------- C[M][N] = A[M][K] @ B[N][K]^T  (m97 structure) ----------------
template<int OUTF32>
__global__ __launch_bounds__(256) void gemm_bt(
    const u16* __restrict__ A, const u16* __restrict__ Bm, void* __restrict__ C,
    int M, int N, int K, float alpha) {
  __shared__ u16 As[128*32];
  __shared__ u16 Bs[128*32];
  const int t = threadIdx.x;
  const int l = t & 63, w = t >> 6;
  const int l15 = l & 15, l4 = l >> 4;
  const int row0 = blockIdx.y * 128, col0 = blockIdx.x * 128;
  const int wr = (w >> 1) * 64, wc = (w & 1) * 64;
  f32x4 acc[4][4] = {};
  const int o0 = w*1024 + l*16;

  for (int k0 = 0; k0 < K; k0 += 32) {
    #pragma unroll
    for (int i = 0; i < 2; ++i) {
      int o = i*4096 + o0;
      int r = o >> 6;
      int cb = o & 63;
      gload16((const char*)A + ((size_t)(row0 + r)*K + k0)*2 + cb,
              (char*)As + i*4096 + w*1024);
      gload16((const char*)Bm + ((size_t)(col0 + r)*K + k0)*2 + cb,
              (char*)Bs + i*4096 + w*1024);
    }
    __syncthreads();
    bf16x8 af[4], bfr[4];
    #pragma unroll
    for (int mi = 0; mi < 4; ++mi)
      af[mi] = *(const bf16x8*)&As[(wr + mi*16 + l15)*32 + l4*8];
    #pragma unroll
    for (int ni = 0; ni < 4; ++ni)
      bfr[ni] = *(const bf16x8*)&Bs[(wc + ni*16 + l15)*32 + l4*8];
    #pragma unroll
    for (int mi = 0; mi < 4; ++mi)
      #pragma unroll
      for (int ni = 0; ni < 4; ++ni)
        acc[mi][ni] = __builtin_amdgcn_mfma_f32_16x16x32_bf16(af[mi], bfr[ni], acc[mi][ni], 0, 0, 0);
    __syncthreads();
  }

  #pragma unroll
  for (int mi = 0; mi < 4; ++mi) {
    #pragma unroll
    for (int ni = 0; ni < 4; ++ni) {
      #pragma unroll
      for (int r = 0; r < 4; ++r) {
        size_t rr = (size_t)(row0 + wr + mi*16 + l4*4 + r);
        size_t cc = (size_t)(col0 + wc + ni*16 + l15);
        float v = acc[mi][ni][r] * alpha;
        if (OUTF32) ((float*)C)[rr*(size_t)N + cc] = v;
        else        ((u16*)C)[rr*(size_t)N + cc] = f2bf(v);
      }
    }
  }
}

// ---------------- causal GQA flash attention, v2 ----------------
// grid (8 pairs, 32 h, 2 b), 256 threads = 4 waves; wave w owns q rows [w*32,w*32+32).
// Each block processes q-tiles qb=pair and qb=15-pair -> constant 36 KVB=64 steps.
// K: LDS rows XOR-swizzled (chunk ^= row&7). V & P: subtiled [*/4][*/16][4][16]
// layouts read via ds_read_b64_tr_b16. 2-phase double-buffered staging.
__global__ __launch_bounds__(256, 2) void attn_kernel(
    const u16* __restrict__ Q,   // [4096][4096]
    const u16* __restrict__ KV,  // [4096][2048]
    u16* __restrict__ O) {       // [4096][4096]
  __shared__ u16 Ks[2][64*128];  // 2 x 16 KB
  __shared__ u16 Vs[2][64*128];  // 2 x 16 KB, subtiled
  __shared__ u16 Ps[4][1024];    // per-wave P^T (one 32-kv half), subtiled
  const int t = threadIdx.x;
  const int l = t & 63, w = t >> 6;
  const int l15 = l & 15, l4 = l >> 4;
  const int pair = blockIdx.x, h = blockIdx.y, b = blockIdx.z;
  const int hkv = h >> 2;
  const u16* Kg = KV + (size_t)(b*SS) * KVPITCH + hkv*HD;
  const u16* Vg = Kg + NKV*HD;
  u16* Pw = &Ps[w][0];

  auto stage = [&](u16* Ksb, u16* Vsb, int kv0) {
    const u16* Kr = Kg + (size_t)kv0 * KVPITCH;
    const u16* Vr = Vg + (size_t)kv0 * KVPITCH;
    #pragma unroll
    for (int i = 0; i < 4; ++i) {
      int o = i*4096 + w*1024 + l*16;
      int row = o >> 8;
      int sc = l15 ^ (row & 7);
      gload16((const char*)(Kr + (size_t)row * KVPITCH) + sc*16,
              (char*)Ksb + i*4096 + w*1024);
    }
    #pragma unroll
    for (int i = 0; i < 4; ++i) {
      int cb = i*4 + w;                       // 16 chunks of 1 KB
      int kv = cb*4 + ((l & 7) >> 1);
      int d0 = ((l >> 3) << 4) + (l & 1)*8;
      gload16((const char*)(Vr + (size_t)kv * KVPITCH + d0),
              (char*)Vsb + cb*1024);
    }
  };

  for (int half = 0; half < 2; ++half) {
    const int qb = half ? (15 - pair) : pair;
    const int q0 = qb * 128;
    const int q0w = q0 + w*32;

    // Q fragments: A-operand row=lane&15, k=(lane>>4)*8+j
    const size_t qbase = ((size_t)(b*SS + q0w)) * DIM + h*HD;
    bf16x8 qf[2][4];
    #pragma unroll
    for (int m = 0; m < 2; ++m)
      #pragma unroll
      for (int kd = 0; kd < 4; ++kd)
        qf[m][kd] = *(const bf16x8*)&Q[qbase + (size_t)(m*16 + l15)*DIM + kd*32 + l4*8];

    f32x4 oacc[2][8] = {};
    float mrun[2][4], lrun[2][4];
    #pragma unroll
    for (int m = 0; m < 2; ++m)
      #pragma unroll
      for (int r = 0; r < 4; ++r) { mrun[m][r] = -1e30f; lrun[m][r] = 0.f; }

    const int nst = 2*qb + 2;
    stage(Ks[0], Vs[0], 0);
    WAIT_VM0;
    __builtin_amdgcn_s_barrier();
    SGB0;

    for (int st = 0; st < nst; ++st) {
      const int kv0 = st * 64;
      u16* Ksb = Ks[st & 1];
      u16* Vsb = Vs[st & 1];
      if (st + 1 < nst) stage(Ks[(st+1) & 1], Vs[(st+1) & 1], kv0 + 64);

      if (kv0 <= q0w + 31) {   // wave has unmasked work this step
        // ---- QK^T ----
        f32x4 sacc[2][4] = {};
        __builtin_amdgcn_s_setprio(1);
        #pragma unroll
        for (int kd = 0; kd < 4; ++kd) {
          bf16x8 kf[4];
          #pragma unroll
          for (int n = 0; n < 4; ++n) {
            int row = n*16 + l15;
            int off = (row << 8) | (((kd*4 + l4) ^ (row & 7)) << 4);
            kf[n] = *(const bf16x8*)((const char*)Ksb + off);
          }
          #pragma unroll
          for (int m = 0; m < 2; ++m)
            #pragma unroll
            for (int n = 0; n < 4; ++n)
              sacc[m][n] = __builtin_amdgcn_mfma_f32_16x16x32_bf16(qf[m][kd], kf[n], sacc[m][n], 0, 0, 0);
        }
        __builtin_amdgcn_s_setprio(0);

        // ---- causal mask (only tiles crossing the diagonal) ----
        if (st >= 2*qb) {
          #pragma unroll
          for (int n = 0; n < 4; ++n) {
            int ki = kv0 + n*16 + l15;
            #pragma unroll
            for (int m = 0; m < 2; ++m)
              #pragma unroll
              for (int r = 0; r < 4; ++r) {
                int qi = q0w + m*16 + l4*4 + r;
                if (ki > qi) sacc[m][n][r] = -1e30f;
              }
          }
        }

        // ---- online softmax (DPP row reductions across 16 lanes) ----
        float pr[2][4][4];
        #pragma unroll
        for (int m = 0; m < 2; ++m) {
          #pragma unroll
          for (int r = 0; r < 4; ++r) {
            float s0 = sacc[m][0][r], s1 = sacc[m][1][r];
            float s2 = sacc[m][2][r], s3 = sacc[m][3][r];
            float vm = fmaxf(fmaxf(s0, s1), fmaxf(s2, s3));
            vm = red16_max(vm);
            float mo = mrun[m][r];
            float mnew = fmaxf(mo, vm);
            float al = __expf(mo - mnew);
            float p0 = __expf(s0 - mnew), p1 = __expf(s1 - mnew);
            float p2 = __expf(s2 - mnew), p3 = __expf(s3 - mnew);
            float rs = red16_sum((p0 + p1) + (p2 + p3));
            mrun[m][r] = mnew;
            lrun[m][r] = lrun[m][r]*al + rs;
            #pragma unroll
            for (int dn = 0; dn < 8; ++dn) oacc[m][dn][r] *= al;
            pr[m][r][0] = p0; pr[m][r][1] = p1; pr[m][r][2] = p2; pr[m][r][3] = p3;
          }
        }

        // ---- PV, per 32-kv half ----
        #pragma unroll
        for (int kvh = 0; kvh < 2; ++kvh) {
          // write P^T half, subtiled [kv'/4][q/16][4][16], vector b64
          #pragma unroll
          for (int m = 0; m < 2; ++m)
            #pragma unroll
            for (int nn = 0; nn < 2; ++nn) {
              int n = kvh*2 + nn;
              bf16x4 w4;
              w4[0] = (__bf16)pr[m][0][n]; w4[1] = (__bf16)pr[m][1][n];
              w4[2] = (__bf16)pr[m][2][n]; w4[3] = (__bf16)pr[m][3][n];
              *(bf16x4*)((char*)Pw + ((nn*4 + (l15 >> 2))*2 + m)*128
                                   + (l15 & 3)*32 + l4*8) = w4;
            }
          // A-fragments: P[q=m*16+l15][kv'=l4*8 + jj*4 + j]
          const char* pb = (const char*)Pw + l4*512 + l15*8;
          bf16x4 a00 = tr16(pb);         // m=0 jj=0
          bf16x4 a01 = tr16(pb + 256);   // m=0 jj=1
          bf16x4 a10 = tr16(pb + 128);   // m=1 jj=0
          bf16x4 a11 = tr16(pb + 384);   // m=1 jj=1
          // B-fragments: V[kv = kvh*32 + l4*8 + jj*4 + j][d = dn*16 + l15]
          const char* vb = (const char*)Vsb + l4*2048 + l15*8 + kvh*8192;
          bf16x4 b0[8], b1[8];
          #pragma unroll
          for (int dn = 0; dn < 8; ++dn) {
            b0[dn] = tr16(vb + dn*128);
            b1[dn] = tr16(vb + dn*128 + 1024);
          }
          WAIT_LGKM0; SGB0;
          bf16x8 pa0 = __builtin_shufflevector(a00, a01, 0,1,2,3,4,5,6,7);
          bf16x8 pa1 = __builtin_shufflevector(a10, a11, 0,1,2,3,4,5,6,7);
          __builtin_amdgcn_s_setprio(1);
          #pragma unroll
          for (int dn = 0; dn < 8; ++dn) {
            bf16x8 v8 = __builtin_shufflevector(b0[dn], b1[dn], 0,1,2,3,4,5,6,7);
            oacc[0][dn] = __builtin_amdgcn_mfma_f32_16x16x32_bf16(pa0, v8, oacc[0][dn], 0, 0, 0);
            oacc[1][dn] = __builtin_amdgcn_mfma_f32_16x16x32_bf16(pa1, v8, oacc[1][dn], 0, 0, 0);
          }
          __builtin_amdgcn_s_setprio(0);
        }
      }

      WAIT_VM0;                       // drain this step's prefetch issues only
      __builtin_amdgcn_s_barrier();
      SGB0;
    }

    // ---- epilogue ----
    const size_t obase = ((size_t)(b*SS + q0w)) * DIM + h*HD;
    #pragma unroll
    for (int m = 0; m < 2; ++m) {
      #pragma unroll
      for (int r = 0; r < 4; ++r) {
        float inv = 1.0f / lrun[m][r];
        int srow = m*16 + l4*4 + r;
        #pragma unroll
        for (int dn = 0; dn < 8; ++dn)
          O[obase + (size_t)srow*DIM + dn*16 + l15] = f2bf(oacc[m][dn][r] * inv);
      }
    }
  }
}

extern "C" void kernel_launch(void* const* d_in, const int* in_sizes, int n_in,
                              void* d_out, int out_size, void* d_ws, size_t ws_size,
                              hipStream_t stream) {
  const float* x   = (const float*)d_in[0];
  const float* Wq  = (const float*)d_in[1];
  const float* Wkv = (const float*)d_in[2];
  const float* Wo  = (const float*)d_in[3];

  if (ws_size < (160ull << 20)) return;
  char* ws = (char*)d_ws;
  u16* xb   = (u16*)(ws);                  // 32 MB
  u16* Wqb  = (u16*)(ws + (32ull  << 20)); // 32 MB
  u16* Wkvb = (u16*)(ws + (64ull  << 20)); // 16 MB
  u16* Wob  = (u16*)(ws + (80ull  << 20)); // 32 MB
  u16* Qb   = (u16*)(ws + (112ull << 20)); // 32 MB
  u16* KVb  = (u16*)(ws + (144ull << 20)); // 16 MB
  u16* attnb = xb;                         // alias after projections

  f2b_kernel<<<8192, 256, 0, stream>>>(x,   xb,   2097152);
  f2b_kernel<<<8192, 256, 0, stream>>>(Wq,  Wqb,  2097152);
  f2b_kernel<<<4096, 256, 0, stream>>>(Wkv, Wkvb, 1048576);
  f2b_kernel<<<8192, 256, 0, stream>>>(Wo,  Wob,  2097152);

  gemm_bt<0><<<dim3(32, 32), 256, 0, stream>>>(xb, Wqb,  Qb,  MROWS, 4096, DIM, QSCALE);
  gemm_bt<0><<<dim3(16, 32), 256, 0, stream>>>(xb, Wkvb, KVb, MROWS, 2048, DIM, 1.0f);

  attn_kernel<<<dim3(8, NHEADS, BB), 256, 0, stream>>>(Qb, KVb, attnb);

  gemm_bt<1><<<dim3(32, 32), 256, 0, stream>>>(attnb, Wob, d_out, MROWS, 4096, DIM, 1.0f);
}

// Round 3
// 568.549 us; speedup vs baseline: 2.1301x; 1.2480x over previous
//
#include <hip/hip_runtime.h>

typedef __bf16 bf16x8 __attribute__((ext_vector_type(8)));
typedef __bf16 bf16x4 __attribute__((ext_vector_type(4)));
typedef float f32x4 __attribute__((ext_vector_type(4)));
typedef unsigned short u16;
typedef unsigned short u16x8 __attribute__((ext_vector_type(8)));

#define DIM 4096
#define NHEADS 32
#define NKV 8
#define HD 128
#define BB 2
#define SS 2048
#define MROWS (BB*SS)        // 4096
#define QKVP 6144            // fused QKV row pitch (4096 Q | 1024 K | 1024 V)
#define QSCALE 0.08838834764831843f  // 1/sqrt(128)

#define WAIT_LGKM0 asm volatile("s_waitcnt lgkmcnt(0)" ::: "memory")
#define WAIT_VM0   asm volatile("s_waitcnt vmcnt(0)" ::: "memory")
#define SGB0       __builtin_amdgcn_sched_barrier(0)

__device__ __forceinline__ u16 f2bf(float f) {
  unsigned int u = __float_as_uint(f);
  u += 0x7fffu + ((u >> 16) & 1u);   // round-to-nearest-even
  return (u16)(u >> 16);
}

__device__ __forceinline__ void gload16(const void* g, void* l) {
  __builtin_amdgcn_global_load_lds(
      (const __attribute__((address_space(1))) unsigned int*)g,
      (__attribute__((address_space(3))) unsigned int*)l, 16, 0, 0);
}

__device__ __forceinline__ bf16x4 tr16(const void* p) {
  bf16x4 d;
  asm volatile("ds_read_b64_tr_b16 %0, %1"
               : "=v"(d)
               : "v"((const __attribute__((address_space(3))) u16*)p)
               : "memory");
  return d;
}

template<int CTRL>
__device__ __forceinline__ float dpp_ror(float x) {
  return __int_as_float(__builtin_amdgcn_update_dpp(
      0, __float_as_int(x), CTRL, 0xF, 0xF, false));
}
__device__ __forceinline__ float red16_max(float v) {
  v = fmaxf(v, dpp_ror<0x121>(v));
  v = fmaxf(v, dpp_ror<0x122>(v));
  v = fmaxf(v, dpp_ror<0x124>(v));
  v = fmaxf(v, dpp_ror<0x128>(v));
  return v;
}
__device__ __forceinline__ float red16_sum(float v) {
  v += dpp_ror<0x121>(v);
  v += dpp_ror<0x122>(v);
  v += dpp_ror<0x124>(v);
  v += dpp_ror<0x128>(v);
  return v;
}

// ---------------- fp32 -> bf16 conversion ----------------
__global__ __launch_bounds__(256) void f2b_kernel(const float* __restrict__ in,
                                                  u16* __restrict__ out, int n8) {
  int i = blockIdx.x * 256 + threadIdx.x;
  if (i >= n8) return;
  const float4* in4 = (const float4*)in;
  float4 a = in4[2*(size_t)i];
  float4 b = in4[2*(size_t)i + 1];
  u16x8 o;
  o[0]=f2bf(a.x); o[1]=f2bf(a.y); o[2]=f2bf(a.z); o[3]=f2bf(a.w);
  o[4]=f2bf(b.x); o[5]=f2bf(b.y); o[6]=f2bf(b.z); o[7]=f2bf(b.w);
  ((u16x8*)out)[i] = o;
}

// ---------------- 256x256 / BK=64 / 8-wave GEMM, C = A @ B^T ----------------
// LDS 128 KiB: A,B tiles double-buffered, rows 128B, 16B-chunk XOR-swizzle
// (chunk ^= row&7). Stage-ahead: tile t+1's global_load_lds issued before
// tile t's 4 quadrant-phases; vmcnt(0)+barrier only at tile boundary.
template<int OUTF32>
__global__ __launch_bounds__(512, 2) void gemm256(
    const u16* __restrict__ A, const u16* __restrict__ Bm, void* __restrict__ C,
    int M, int N, int K, int nbx, int acut, float a0, float a1) {
  __shared__ char smem[131072];           // [A0|A1|B0|B1] x 32KB
  char* smA = smem;
  char* smB = smem + 65536;

  const int t = threadIdx.x;
  const int l = t & 63, w = t >> 6;
  const int l15 = l & 15, l4 = l >> 4;
  const int wm = w >> 2, wn = w & 3;      // 2 x 4 wave grid

  // bijective XCD swizzle (nwg % 8 == 0 for all our grids)
  const int nwg = gridDim.x;
  const int cpx = nwg >> 3;
  const int sw = (blockIdx.x & 7) * cpx + (blockIdx.x >> 3);
  const int bx = sw % nbx, by = sw / nbx;
  const int row0 = by * 256, col0 = bx * 256;
  const float alpha = (col0 < acut) ? a0 : a1;

  f32x4 acc[8][4] = {};

  auto stage = [&](int k0, int pb) {
    char* Ad = smA + pb * 32768;
    char* Bd = smB + pb * 32768;
    #pragma unroll
    for (int i = 0; i < 4; ++i) {
      int o = i*8192 + w*1024 + l*16;
      int row = o >> 7;                    // 128B per row (64 bf16)
      int sc = ((o >> 4) & 7) ^ (row & 7); // pre-swizzled source chunk
      gload16((const char*)A + ((size_t)(row0 + row)*K + k0)*2 + sc*16,
              Ad + i*8192 + w*1024);
      gload16((const char*)Bm + ((size_t)(col0 + row)*K + k0)*2 + sc*16,
              Bd + i*8192 + w*1024);
    }
  };

  const int ntiles = K >> 6;
  stage(0, 0);
  WAIT_VM0;
  __builtin_amdgcn_s_barrier();

  for (int kt = 0; kt < ntiles; ++kt) {
    const char* Ab = smA + (kt & 1) * 32768;
    const char* Bb = smB + (kt & 1) * 32768;
    if (kt + 1 < ntiles) stage((kt + 1) << 6, (kt + 1) & 1);

    #pragma unroll
    for (int q = 0; q < 4; ++q) {
      const int qm = q >> 1, qn = q & 1;
      bf16x8 af[4][2], bfv[2][2];
      #pragma unroll
      for (int mi = 0; mi < 4; ++mi)
        #pragma unroll
        for (int kk = 0; kk < 2; ++kk) {
          int row = wm*128 + (qm*4 + mi)*16 + l15;
          int sc = (kk*4 + l4) ^ (row & 7);
          af[mi][kk] = *(const bf16x8*)(Ab + row*128 + sc*16);
        }
      #pragma unroll
      for (int ni = 0; ni < 2; ++ni)
        #pragma unroll
        for (int kk = 0; kk < 2; ++kk) {
          int row = wn*64 + (qn*2 + ni)*16 + l15;
          int sc = (kk*4 + l4) ^ (row & 7);
          bfv[ni][kk] = *(const bf16x8*)(Bb + row*128 + sc*16);
        }
      __builtin_amdgcn_s_setprio(1);
      #pragma unroll
      for (int kk = 0; kk < 2; ++kk)
        #pragma unroll
        for (int mi = 0; mi < 4; ++mi)
          #pragma unroll
          for (int ni = 0; ni < 2; ++ni)
            acc[qm*4 + mi][qn*2 + ni] = __builtin_amdgcn_mfma_f32_16x16x32_bf16(
                af[mi][kk], bfv[ni][kk], acc[qm*4 + mi][qn*2 + ni], 0, 0, 0);
      __builtin_amdgcn_s_setprio(0);
      __builtin_amdgcn_s_barrier();       // lockstep (raw barrier: no drain)
    }
    WAIT_VM0;                             // own stage insts for tile kt+1
    __builtin_amdgcn_s_barrier();
  }

  // epilogue: C/D layout col=lane&15, row=(lane>>4)*4+reg
  #pragma unroll
  for (int mi = 0; mi < 8; ++mi) {
    #pragma unroll
    for (int ni = 0; ni < 4; ++ni) {
      #pragma unroll
      for (int r = 0; r < 4; ++r) {
        size_t rr = (size_t)(row0 + wm*128 + mi*16 + l4*4 + r);
        size_t cc = (size_t)(col0 + wn*64 + ni*16 + l15);
        float v = acc[mi][ni][r] * alpha;
        if (OUTF32) ((float*)C)[rr*(size_t)N + cc] = v;
        else        ((u16*)C)[rr*(size_t)N + cc] = f2bf(v);
      }
    }
  }
}

// ---------------- causal GQA flash attention (round-2 version, QKVP pitch) ----------------
__global__ __launch_bounds__(256, 2) void attn_kernel(
    const u16* __restrict__ QKV,  // [4096][6144]: 0..4095 Q | 4096..5119 K | 5120..6143 V
    u16* __restrict__ O) {        // [4096][4096]
  __shared__ u16 Ks[2][64*128];
  __shared__ u16 Vs[2][64*128];
  __shared__ u16 Ps[4][1024];
  const int t = threadIdx.x;
  const int l = t & 63, w = t >> 6;
  const int l15 = l & 15, l4 = l >> 4;
  const int pair = blockIdx.x, h = blockIdx.y, b = blockIdx.z;
  const int hkv = h >> 2;
  const u16* Kg = QKV + (size_t)(b*SS) * QKVP + DIM + hkv*HD;
  const u16* Vg = Kg + NKV*HD;
  u16* Pw = &Ps[w][0];

  auto stage = [&](u16* Ksb, u16* Vsb, int kv0) {
    const u16* Kr = Kg + (size_t)kv0 * QKVP;
    const u16* Vr = Vg + (size_t)kv0 * QKVP;
    #pragma unroll
    for (int i = 0; i < 4; ++i) {
      int o = i*4096 + w*1024 + l*16;
      int row = o >> 8;
      int sc = l15 ^ (row & 7);
      gload16((const char*)(Kr + (size_t)row * QKVP) + sc*16,
              (char*)Ksb + i*4096 + w*1024);
    }
    #pragma unroll
    for (int i = 0; i < 4; ++i) {
      int cb = i*4 + w;
      int kv = cb*4 + ((l & 7) >> 1);
      int d0 = ((l >> 3) << 4) + (l & 1)*8;
      gload16((const char*)(Vr + (size_t)kv * QKVP + d0),
              (char*)Vsb + cb*1024);
    }
  };

  for (int half = 0; half < 2; ++half) {
    const int qb = half ? (15 - pair) : pair;
    const int q0 = qb * 128;
    const int q0w = q0 + w*32;

    const size_t qbase = ((size_t)(b*SS + q0w)) * QKVP + h*HD;
    bf16x8 qf[2][4];
    #pragma unroll
    for (int m = 0; m < 2; ++m)
      #pragma unroll
      for (int kd = 0; kd < 4; ++kd)
        qf[m][kd] = *(const bf16x8*)&QKV[qbase + (size_t)(m*16 + l15)*QKVP + kd*32 + l4*8];

    f32x4 oacc[2][8] = {};
    float mrun[2][4], lrun[2][4];
    #pragma unroll
    for (int m = 0; m < 2; ++m)
      #pragma unroll
      for (int r = 0; r < 4; ++r) { mrun[m][r] = -1e30f; lrun[m][r] = 0.f; }

    const int nst = 2*qb + 2;
    stage(Ks[0], Vs[0], 0);
    WAIT_VM0;
    __builtin_amdgcn_s_barrier();
    SGB0;

    for (int st = 0; st < nst; ++st) {
      const int kv0 = st * 64;
      u16* Ksb = Ks[st & 1];
      u16* Vsb = Vs[st & 1];
      if (st + 1 < nst) stage(Ks[(st+1) & 1], Vs[(st+1) & 1], kv0 + 64);

      if (kv0 <= q0w + 31) {
        f32x4 sacc[2][4] = {};
        __builtin_amdgcn_s_setprio(1);
        #pragma unroll
        for (int kd = 0; kd < 4; ++kd) {
          bf16x8 kf[4];
          #pragma unroll
          for (int n = 0; n < 4; ++n) {
            int row = n*16 + l15;
            int off = (row << 8) | (((kd*4 + l4) ^ (row & 7)) << 4);
            kf[n] = *(const bf16x8*)((const char*)Ksb + off);
          }
          #pragma unroll
          for (int m = 0; m < 2; ++m)
            #pragma unroll
            for (int n = 0; n < 4; ++n)
              sacc[m][n] = __builtin_amdgcn_mfma_f32_16x16x32_bf16(qf[m][kd], kf[n], sacc[m][n], 0, 0, 0);
        }
        __builtin_amdgcn_s_setprio(0);

        if (st >= 2*qb) {
          #pragma unroll
          for (int n = 0; n < 4; ++n) {
            int ki = kv0 + n*16 + l15;
            #pragma unroll
            for (int m = 0; m < 2; ++m)
              #pragma unroll
              for (int r = 0; r < 4; ++r) {
                int qi = q0w + m*16 + l4*4 + r;
                if (ki > qi) sacc[m][n][r] = -1e30f;
              }
          }
        }

        float pr[2][4][4];
        #pragma unroll
        for (int m = 0; m < 2; ++m) {
          #pragma unroll
          for (int r = 0; r < 4; ++r) {
            float s0 = sacc[m][0][r], s1 = sacc[m][1][r];
            float s2 = sacc[m][2][r], s3 = sacc[m][3][r];
            float vm = fmaxf(fmaxf(s0, s1), fmaxf(s2, s3));
            vm = red16_max(vm);
            float mo = mrun[m][r];
            float mnew = fmaxf(mo, vm);
            float al = __expf(mo - mnew);
            float p0 = __expf(s0 - mnew), p1 = __expf(s1 - mnew);
            float p2 = __expf(s2 - mnew), p3 = __expf(s3 - mnew);
            float rs = red16_sum((p0 + p1) + (p2 + p3));
            mrun[m][r] = mnew;
            lrun[m][r] = lrun[m][r]*al + rs;
            #pragma unroll
            for (int dn = 0; dn < 8; ++dn) oacc[m][dn][r] *= al;
            pr[m][r][0] = p0; pr[m][r][1] = p1; pr[m][r][2] = p2; pr[m][r][3] = p3;
          }
        }

        #pragma unroll
        for (int kvh = 0; kvh < 2; ++kvh) {
          #pragma unroll
          for (int m = 0; m < 2; ++m)
            #pragma unroll
            for (int nn = 0; nn < 2; ++nn) {
              int n = kvh*2 + nn;
              bf16x4 w4;
              w4[0] = (__bf16)pr[m][0][n]; w4[1] = (__bf16)pr[m][1][n];
              w4[2] = (__bf16)pr[m][2][n]; w4[3] = (__bf16)pr[m][3][n];
              *(bf16x4*)((char*)Pw + ((nn*4 + (l15 >> 2))*2 + m)*128
                                   + (l15 & 3)*32 + l4*8) = w4;
            }
          const char* pb = (const char*)Pw + l4*512 + l15*8;
          bf16x4 a00 = tr16(pb);
          bf16x4 a01 = tr16(pb + 256);
          bf16x4 a10 = tr16(pb + 128);
          bf16x4 a11 = tr16(pb + 384);
          const char* vb = (const char*)Vsb + l4*2048 + l15*8 + kvh*8192;
          bf16x4 b0[8], b1[8];
          #pragma unroll
          for (int dn = 0; dn < 8; ++dn) {
            b0[dn] = tr16(vb + dn*128);
            b1[dn] = tr16(vb + dn*128 + 1024);
          }
          WAIT_LGKM0; SGB0;
          bf16x8 pa0 = __builtin_shufflevector(a00, a01, 0,1,2,3,4,5,6,7);
          bf16x8 pa1 = __builtin_shufflevector(a10, a11, 0,1,2,3,4,5,6,7);
          __builtin_amdgcn_s_setprio(1);
          #pragma unroll
          for (int dn = 0; dn < 8; ++dn) {
            bf16x8 v8 = __builtin_shufflevector(b0[dn], b1[dn], 0,1,2,3,4,5,6,7);
            oacc[0][dn] = __builtin_amdgcn_mfma_f32_16x16x32_bf16(pa0, v8, oacc[0][dn], 0, 0, 0);
            oacc[1][dn] = __builtin_amdgcn_mfma_f32_16x16x32_bf16(pa1, v8, oacc[1][dn], 0, 0, 0);
          }
          __builtin_amdgcn_s_setprio(0);
        }
      }

      WAIT_VM0;
      __builtin_amdgcn_s_barrier();
      SGB0;
    }

    const size_t obase = ((size_t)(b*SS + q0w)) * DIM + h*HD;
    #pragma unroll
    for (int m = 0; m < 2; ++m) {
      #pragma unroll
      for (int r = 0; r < 4; ++r) {
        float inv = 1.0f / lrun[m][r];
        int srow = m*16 + l4*4 + r;
        #pragma unroll
        for (int dn = 0; dn < 8; ++dn)
          O[obase + (size_t)srow*DIM + dn*16 + l15] = f2bf(oacc[m][dn][r] * inv);
      }
    }
  }
}

extern "C" void kernel_launch(void* const* d_in, const int* in_sizes, int n_in,
                              void* d_out, int out_size, void* d_ws, size_t ws_size,
                              hipStream_t stream) {
  const float* x   = (const float*)d_in[0];
  const float* Wq  = (const float*)d_in[1];
  const float* Wkv = (const float*)d_in[2];
  const float* Wo  = (const float*)d_in[3];

  if (ws_size < (160ull << 20)) return;
  char* ws = (char*)d_ws;
  u16* xb   = (u16*)(ws);                  // 32 MB [4096][4096]
  u16* Wqb  = (u16*)(ws + (32ull  << 20)); // 32 MB [4096][4096]  \ fused W: rows 0..6143
  u16* Wkvb = (u16*)(ws + (64ull  << 20)); // 16 MB [2048][4096]  /
  u16* Wob  = (u16*)(ws + (80ull  << 20)); // 32 MB [4096][4096]
  u16* QKVb = (u16*)(ws + (112ull << 20)); // 48 MB [4096][6144]
  u16* attnb = xb;                         // alias after projections

  f2b_kernel<<<8192, 256, 0, stream>>>(x,   xb,   2097152);
  f2b_kernel<<<8192, 256, 0, stream>>>(Wq,  Wqb,  2097152);
  f2b_kernel<<<4096, 256, 0, stream>>>(Wkv, Wkvb, 1048576);
  f2b_kernel<<<8192, 256, 0, stream>>>(Wo,  Wob,  2097152);

  // fused QKV projection: [4096][6144] = xb @ [Wq;Wkv]^T ; QSCALE on Q cols only
  gemm256<0><<<dim3(16*24), 512, 0, stream>>>(xb, Wqb, QKVb,
                                              MROWS, QKVP, DIM, 24, DIM, QSCALE, 1.0f);

  attn_kernel<<<dim3(8, NHEADS, BB), 256, 0, stream>>>(QKVb, attnb);

  // output projection (fp32 out)
  gemm256<1><<<dim3(16*16), 512, 0, stream>>>(attnb, Wob, d_out,
                                              MROWS, DIM, DIM, 16, 0, 1.0f, 1.0f);
}